// Round 4
// baseline (3241.736 us; speedup 1.0000x reference)
//
#include <hip/hip_runtime.h>

// Problem constants
#define BB 2048   // batch
#define TT 128    // timesteps
#define VV 25     // input features
#define HH 512    // hidden
#define NC 100    // classes

typedef __attribute__((ext_vector_type(8))) _Float16 half8;
typedef __attribute__((ext_vector_type(4))) float f32x4;

__device__ __forceinline__ float fsigmoid(float x) { return 1.0f / (1.0f + __expf(-x)); }
__device__ __forceinline__ float ftanh(float x) {
    float e = __expf(2.0f * x);
    return 1.0f - 2.0f / (e + 1.0f);
}

// ---- coherent (agent-scope, L1/L2-bypass) h exchange ----
// sc0 sc1 loads/stores are coherent at the Infinity-Cache point, so group
// blocks on different XCDs see each other's h WITHOUT any L2 invalidate —
// WT stays hot in L2 across all 128 steps (the launch-per-step scheme paid
// a full L2 wb_inv + WT refetch from L3 at every kernel boundary).
__device__ __forceinline__ half8 gload_c(const _Float16* p) {
    half8 r;
    asm volatile("global_load_dwordx4 %0, %1, off sc0 sc1" : "=v"(r) : "v"(p) : "memory");
    return r;
}
__device__ __forceinline__ void gstore_c(_Float16* p, _Float16 v) {
    asm volatile("global_store_short %0, %1, off sc0 sc1" :: "v"(p), "v"(v) : "memory");
}
__device__ __forceinline__ void wait_vm0() {
    asm volatile("s_waitcnt vmcnt(0)" ::: "memory");
    __builtin_amdgcn_sched_barrier(0);
}
// counted wait: ra (2 asm loads) retired; this-iteration's 8 B-weight loads
// stay in flight (they are the ONLY vm ops issued after ra — pinned by the
// surrounding memory-clobber asm, so the count is exact).
__device__ __forceinline__ void wait_vm8() {
    asm volatile("s_waitcnt vmcnt(8)" ::: "memory");
    __builtin_amdgcn_sched_barrier(0);
}
// LDS-only barrier (global prefetches stay in flight across it).
__device__ __forceinline__ void bar_lgkm() {
    asm volatile("s_waitcnt lgkmcnt(0)" ::: "memory");
    __builtin_amdgcn_sched_barrier(0);
    __builtin_amdgcn_s_barrier();
    asm volatile("" ::: "memory");
}

// ---- prep: weights -> MFMA-fragment-native fp16 layout ----
// WT[kq][n] : 16B group = fp16(W[n][kq*8 .. kq*8+7])  (kq 0..63 = W_hh,
// 64..67 = W_ih zero-padded to K=32).
__global__ __launch_bounds__(256) void prep_whh_t(const float* __restrict__ W,
                                                  _Float16* __restrict__ WT) {
    int i = blockIdx.x * 256 + threadIdx.x;   // 2048 n x 64 kq, grid 512
    int n = i & 2047, kq = i >> 11;
    half8 h8;
    #pragma unroll
    for (int j = 0; j < 8; ++j) h8[j] = (_Float16)W[(size_t)n * HH + kq * 8 + j];  // RNE cvt
    ((half8*)WT)[(size_t)kq * 2048 + n] = h8;
}

__global__ __launch_bounds__(256) void prep_wih_t(const float* __restrict__ W,
                                                  _Float16* __restrict__ WT) {
    int i = blockIdx.x * 256 + threadIdx.x;   // 2048 n x 4 kq, grid 32
    int n = i & 2047, kq4 = i >> 11;
    half8 h8;
    #pragma unroll
    for (int j = 0; j < 8; ++j) {
        int k = kq4 * 8 + j;
        h8[j] = (k < VV) ? (_Float16)W[(size_t)n * VV + k] : (_Float16)0.0f;
    }
    ((half8*)WT)[(size_t)(64 + kq4) * 2048 + n] = h8;
}

// Persistent LSTM: ALL 128 timesteps in one launch.
//
// The batch decomposes into 32 independent groups of 64 rows; only the 16
// j-blocks of a group exchange h per step. Group-local barrier = atomic
// counter (monotonic, 16 arrivals/step) + spin on thread 0. Groups
// free-run relative to each other. Deadlock-free by capacity: 2 blocks/CU
// (LDS 18.4KB, VGPR<256) = 512 slots for 512 blocks; even under partial
// residency, workgroups dispatch in ID order and whole groups retire,
// freeing slots for the next group's members.
//
// Per step (proven r8/1558us inner structure, LDS-staged A, register B):
//  - c entirely in REGISTERS (cv[2][4]) — its 8MB/step of traffic is gone.
//  - x-values (t+1) and B chunks 0,1 prefetched BEFORE the group barrier
//    (h-independent; WT is read-only so no staleness) — they land during
//    the spin, for free.
//  - in-loop: counted wait_vm8 before each ds_write (ra ready, B prefetch
//    for the NEXT chunk stays in flight — vmcnt never drains to 0), and
//    lgkm-only barriers.
//  - h writes: sc0sc1 write-through; drained by the pre-arrival
//    __syncthreads (vmcnt 0); arrival add carries RELEASE (wbl2, no inv).
//    h reads: sc0sc1 bypass — no acquire-invalidate anywhere, L2/WT hot.
__global__ __launch_bounds__(256, 2) void lstm_persist(
    const float* __restrict__ msg,
    const _Float16* __restrict__ WT,
    const float* __restrict__ b_ih, const float* __restrict__ b_hh,
    _Float16* __restrict__ h0g, _Float16* __restrict__ h1g,
    unsigned* __restrict__ ctr)
{
    const int bx = blockIdx.x;
    const int grp = bx >> 4;            // batch group: 64 rows
    const int b0 = grp * 64;
    const int j0 = (bx & 15) * 32;
    const int tid = threadIdx.x;
    const int lane = tid & 63;
    const int w = tid >> 6;
    const int wm = w & 1, wn = w >> 1;
    const int col = lane & 15, quad = lane >> 4;
    const int jj = j0 + wn * 16 + col;

    // [buf][row][k]; row stride 72 halves: frag b128 reads conflict-free.
    __shared__ _Float16 Abuf[2][64][72];

    // ---- loop-invariant state ----
    float bias[4];
    #pragma unroll
    for (int g = 0; g < 4; ++g) bias[g] = b_ih[g * HH + jj] + b_hh[g * HH + jj];

    const int arow = tid >> 2, aseg = (tid & 3) << 4;
    const size_t aoff = (size_t)(b0 + arow) * HH + aseg;
    const _Float16* a0 = h0g + aoff;    // A staging base per h-plane
    const _Float16* a1 = h1g + aoff;

    const half8* WT8 = (const half8*)WT;
    int bidx[4];
    #pragma unroll
    for (int g = 0; g < 4; ++g) bidx[g] = quad * 2048 + g * HH + jj;

    // h store base: rows b0+wm*32+quad*4 (+ tm*16 + reg)
    const size_t soff = (size_t)(b0 + wm * 32 + quad * 4) * HH + jj;
    _Float16* s0 = h0g + soff;
    _Float16* s1 = h1g + soff;

    unsigned* cnt = ctr + grp * 16;     // 64B-padded counter per group

    float cv[2][4] = {{0.f,0.f,0.f,0.f},{0.f,0.f,0.f,0.f}};  // c in registers

    const float* mp[2];
    #pragma unroll
    for (int tm = 0; tm < 2; ++tm)
        mp[tm] = msg + (size_t)(b0 + wm * 32 + tm * 16 + col) * TT * VV;

    // x-values for t=0 (direct A-fragment layout: row=...+col, k=quad*8+j)
    float xv[2][8];
    #pragma unroll
    for (int tm = 0; tm < 2; ++tm)
        #pragma unroll
        for (int j = 0; j < 8; ++j) {
            int k = quad * 8 + j;
            xv[tm][j] = (k < VV) ? mp[tm][k] : 0.0f;
        }

    half8 Bs[2][4];
    #pragma unroll
    for (int g = 0; g < 4; ++g) Bs[0][g] = WT8[16 * 8192 + bidx[g]];  // x-tail B (t=0)

    for (int t = 0; t < TT; ++t) {
        f32x4 acc[2][4];
        #pragma unroll
        for (int g = 0; g < 4; ++g) {
            f32x4 bv = {bias[g], bias[g], bias[g], bias[g]};
            acc[0][g] = bv;
            acc[1][g] = bv;
        }

        if (t > 0) {   // h-projection (t=0: h==0, skip; cv==0 handles c)
            const _Float16* aph = (t & 1) ? a1 : a0;   // hin = hb[t&1]

            // prologue: A chunk0 -> LDS buf0; chunk1 -> ra. (Bs[0]=c0,
            // Bs[1]=c1 were prefetched before the previous barrier.)
            half8 ra0 = gload_c(aph);
            half8 ra1 = gload_c(aph + 8);
            wait_vm0();
            *(half8*)&Abuf[0][arow][aseg]     = ra0;
            *(half8*)&Abuf[0][arow][aseg + 8] = ra1;
            ra0 = gload_c(aph + 64);
            ra1 = gload_c(aph + 72);
            bar_lgkm();

            #pragma unroll
            for (int it = 0; it < 8; ++it) {
                const int buf = it & 1;
                #pragma unroll
                for (int kk = 0; kk < 2; ++kk) {
                    const int cc = it * 2 + kk;   // K32 chunk 0..15
                    const int sl = cc & 1;
                    half8 ahf[2];
                    #pragma unroll
                    for (int tm = 0; tm < 2; ++tm)
                        ahf[tm] = *(const half8*)&Abuf[buf][wm * 32 + tm * 16 + col][kk * 32 + quad * 8];
                    #pragma unroll
                    for (int tm = 0; tm < 2; ++tm)
                        #pragma unroll
                        for (int g = 0; g < 4; ++g)
                            acc[tm][g] = __builtin_amdgcn_mfma_f32_16x16x32_f16(ahf[tm], Bs[sl][g], acc[tm][g], 0, 0, 0);
                    const int pf = cc + 2;        // chunk 16 = Wih tail
                    if (pf <= 16) {
                        #pragma unroll
                        for (int g = 0; g < 4; ++g) Bs[sl][g] = WT8[pf * 8192 + bidx[g]];
                    }
                }
                if (it < 7) {
                    wait_vm8();   // ra retired; 8 B loads stay in flight
                    *(half8*)&Abuf[buf ^ 1][arow][aseg]     = ra0;
                    *(half8*)&Abuf[buf ^ 1][arow][aseg + 8] = ra1;
                    if (it < 6) {
                        ra0 = gload_c(aph + (it + 2) * 64);
                        ra1 = gload_c(aph + (it + 2) * 64 + 8);
                    }
                    bar_lgkm();
                }
            }
        }

        // ---- x-projection tail: chunk 16 in Bs[0] ----
        {
            half8 ahf[2];
            #pragma unroll
            for (int tm = 0; tm < 2; ++tm) {
                half8 xh;
                #pragma unroll
                for (int j = 0; j < 8; ++j) xh[j] = (_Float16)xv[tm][j];
                ahf[tm] = xh;
            }
            #pragma unroll
            for (int tm = 0; tm < 2; ++tm)
                #pragma unroll
                for (int g = 0; g < 4; ++g)
                    acc[tm][g] = __builtin_amdgcn_mfma_f32_16x16x32_f16(ahf[tm], Bs[0][g], acc[tm][g], 0, 0, 0);
        }

        // ---- cell update: c in registers; coherent h stores ----
        // C/D layout: col=lane&15 (=n), row=quad*4+reg  [m89]
        _Float16* hop = (t & 1) ? s0 : s1;      // hout = hb[(t&1)^1]
        #pragma unroll
        for (int tm = 0; tm < 2; ++tm)
            #pragma unroll
            for (int reg = 0; reg < 4; ++reg) {
                float i_ = fsigmoid(acc[tm][0][reg]);
                float f_ = fsigmoid(acc[tm][1][reg]);
                float g_ = ftanh(acc[tm][2][reg]);
                float o_ = fsigmoid(acc[tm][3][reg]);
                float cn = __builtin_fmaf(f_, cv[tm][reg], i_ * g_);
                cv[tm][reg] = cn;
                gstore_c(hop + (size_t)(tm * 16 + reg) * HH, (_Float16)(o_ * ftanh(cn)));
            }

        if (t + 1 < TT) {
            // ---- t+1 prefetch (h-independent; lands during the spin) ----
            #pragma unroll
            for (int tm = 0; tm < 2; ++tm) mp[tm] += VV;
            #pragma unroll
            for (int tm = 0; tm < 2; ++tm)
                #pragma unroll
                for (int j = 0; j < 8; ++j) {
                    int k = quad * 8 + j;
                    xv[tm][j] = (k < VV) ? mp[tm][k] : 0.0f;
                }
            #pragma unroll
            for (int g = 0; g < 4; ++g) {
                Bs[0][g] = WT8[bidx[g]];
                Bs[1][g] = WT8[8192 + bidx[g]];
            }

            // ---- group barrier ----
            __syncthreads();   // vmcnt(0): all h stores at the coherence point
            if (tid == 0) {
                __hip_atomic_fetch_add(cnt, 1u, __ATOMIC_RELEASE, __HIP_MEMORY_SCOPE_AGENT);
                const unsigned tgt = 16u * (unsigned)(t + 1);
                while (__hip_atomic_load(cnt, __ATOMIC_RELAXED, __HIP_MEMORY_SCOPE_AGENT) < tgt)
                    __builtin_amdgcn_s_sleep(2);
            }
            __syncthreads();
        }
    }
}

// out[b, cls] = dot(h, W_fc[cls]) + b_fc[cls]. 4 rows/block.
__global__ __launch_bounds__(256) void fc_kernel(
    const _Float16* __restrict__ h, const float* __restrict__ W_fc,
    const float* __restrict__ b_fc, float* __restrict__ out)
{
    __shared__ float hs[4][HH];
    const int b0 = blockIdx.x * 4;
    for (int i = threadIdx.x; i < 4 * HH; i += 256) {
        int r = i >> 9, k = i & 511;
        hs[r][k] = (float)h[(size_t)(b0 + r) * HH + k];
    }
    __syncthreads();
    const int tid = threadIdx.x;
    if (tid < 2 * NC) {
        int r = tid / NC, cls = tid % NC;
        const float4* wv = (const float4*)(W_fc + (size_t)cls * HH);
        const float4* h0 = (const float4*)hs[r];
        const float4* h1 = (const float4*)hs[r + 2];
        float s0 = 0.0f, s1 = 0.0f;
        #pragma unroll 4
        for (int k = 0; k < HH / 4; ++k) {
            float4 ww = wv[k];
            float4 a0 = h0[k], a1 = h1[k];
            s0 += a0.x * ww.x + a0.y * ww.y + a0.z * ww.z + a0.w * ww.w;
            s1 += a1.x * ww.x + a1.y * ww.y + a1.z * ww.z + a1.w * ww.w;
        }
        out[(size_t)(b0 + r) * NC + cls] = s0 + b_fc[cls];
        out[(size_t)(b0 + r + 2) * NC + cls] = s1 + b_fc[cls];
    }
}

extern "C" void kernel_launch(void* const* d_in, const int* in_sizes, int n_in,
                              void* d_out, int out_size, void* d_ws, size_t ws_size,
                              hipStream_t stream) {
    const float* msg  = (const float*)d_in[0];
    const float* W_ih = (const float*)d_in[1];
    const float* W_hh = (const float*)d_in[2];
    const float* b_ih = (const float*)d_in[3];
    const float* b_hh = (const float*)d_in[4];
    const float* W_fc = (const float*)d_in[5];
    const float* b_fc = (const float*)d_in[6];
    float* out = (float*)d_out;

    // ws: h0 h1 (fp16, 2MB ea) | WT (fp16, 2.23MB) | ctr (2KB). c is in
    // registers now; t==0 reads neither h nor c, so no big memset.
    _Float16* h0 = (_Float16*)d_ws;
    _Float16* h1 = h0 + (size_t)BB * HH;
    _Float16* WT = h1 + (size_t)BB * HH;
    unsigned* ctr = (unsigned*)(WT + (size_t)68 * 2048 * 8);

    hipMemsetAsync(ctr, 0, 32 * 16 * sizeof(unsigned), stream);

    prep_whh_t<<<512, 256, 0, stream>>>(W_hh, WT);
    prep_wih_t<<<32, 256, 0, stream>>>(W_ih, WT);

    lstm_persist<<<512, 256, 0, stream>>>(msg, WT, b_ih, b_hh, h0, h1, ctr);

    // t=127 (odd) writes h0
    fc_kernel<<<BB / 4, 256, 0, stream>>>(h0, W_fc, b_fc, out);
}

// Round 5
// 1933.861 us; speedup vs baseline: 1.6763x; 1.6763x over previous
//
#include <hip/hip_runtime.h>

// Problem constants
#define BB 2048   // batch
#define TT 128    // timesteps
#define VV 25     // input features
#define HH 512    // hidden
#define NC 100    // classes

typedef __attribute__((ext_vector_type(8))) _Float16 half8;
typedef __attribute__((ext_vector_type(4))) float f32x4;

__device__ __forceinline__ float fsigmoid(float x) { return 1.0f / (1.0f + __expf(-x)); }
__device__ __forceinline__ float ftanh(float x) {
    float e = __expf(2.0f * x);
    return 1.0f - 2.0f / (e + 1.0f);
}

// ---- XCD-L2-coherent h exchange ----
// Round 4's sc0sc1 (device/system-scope) ops pushed 1.7GB of h traffic to
// HBM (FETCH_SIZE counter) — the regression. Fix: all 16 communicating
// blocks of a group are placed on ONE XCD (bx%8 round-robin mapping,
// reliable for full 2-block/CU grids per m157/m192), so the shared XCD L2
// IS the coherence point:
//   stores: plain (CDNA vector L1 is write-through -> lands in XCD L2)
//   loads:  sc0 only (bypass per-CU L1, which may hold 2-step-stale lines)
//   barrier: RELAXED atomics; pre-arrival __syncthreads drains vmcnt(0)
//            so stores are retired into L2 before the arrival add.
__device__ __forceinline__ half8 gload_l2(const _Float16* p) {
    half8 r;
    asm volatile("global_load_dwordx4 %0, %1, off sc0" : "=v"(r) : "v"(p) : "memory");
    return r;
}
__device__ __forceinline__ void wait_vm0() {
    asm volatile("s_waitcnt vmcnt(0)" ::: "memory");
    __builtin_amdgcn_sched_barrier(0);
}
// counted wait: ra (2 asm loads) retired; this-iteration's 8 B-weight loads
// stay in flight (the only vm ops issued after ra — memory-clobber asm pins
// the plain B loads on their side, so the count is exact).
__device__ __forceinline__ void wait_vm8() {
    asm volatile("s_waitcnt vmcnt(8)" ::: "memory");
    __builtin_amdgcn_sched_barrier(0);
}
// LDS-only barrier (global prefetches stay in flight across it).
__device__ __forceinline__ void bar_lgkm() {
    asm volatile("s_waitcnt lgkmcnt(0)" ::: "memory");
    __builtin_amdgcn_sched_barrier(0);
    __builtin_amdgcn_s_barrier();
    asm volatile("" ::: "memory");
}

// ---- prep: weights -> MFMA-fragment-native fp16 layout ----
// WT[kq][n] : 16B group = fp16(W[n][kq*8 .. kq*8+7])  (kq 0..63 = W_hh,
// 64..67 = W_ih zero-padded to K=32).
__global__ __launch_bounds__(256) void prep_whh_t(const float* __restrict__ W,
                                                  _Float16* __restrict__ WT) {
    int i = blockIdx.x * 256 + threadIdx.x;   // 2048 n x 64 kq, grid 512
    int n = i & 2047, kq = i >> 11;
    half8 h8;
    #pragma unroll
    for (int j = 0; j < 8; ++j) h8[j] = (_Float16)W[(size_t)n * HH + kq * 8 + j];  // RNE cvt
    ((half8*)WT)[(size_t)kq * 2048 + n] = h8;
}

__global__ __launch_bounds__(256) void prep_wih_t(const float* __restrict__ W,
                                                  _Float16* __restrict__ WT) {
    int i = blockIdx.x * 256 + threadIdx.x;   // 2048 n x 4 kq, grid 32
    int n = i & 2047, kq4 = i >> 11;
    half8 h8;
    #pragma unroll
    for (int j = 0; j < 8; ++j) {
        int k = kq4 * 8 + j;
        h8[j] = (k < VV) ? (_Float16)W[(size_t)n * VV + k] : (_Float16)0.0f;
    }
    ((half8*)WT)[(size_t)(64 + kq4) * 2048 + n] = h8;
}

// Persistent LSTM: ALL 128 timesteps in one launch. Identical protocol to
// round 4 (correctness-proven: group atomic barrier, double-buffered h
// planes, c in registers, x/B prefetch over the spin) — only the h
// transport changed (XCD-local L2 instead of sc0sc1 near-HBM ops) plus the
// block remap that makes each group XCD-local:
//   grp = (bx&7) | ((bx>>7)<<3), member = (bx>>3)&15
// -> the 16 members of grp share bx%8 (one XCD); 4 groups per XCD.
// Deadlock-free by capacity: 2 blocks/CU (LDS 18.4KB) = 512 slots for 512
// blocks, all co-resident (proven by round 4's passing run).
__global__ __launch_bounds__(256, 2) void lstm_persist(
    const float* __restrict__ msg,
    const _Float16* __restrict__ WT,
    const float* __restrict__ b_ih, const float* __restrict__ b_hh,
    _Float16* __restrict__ h0g, _Float16* __restrict__ h1g,
    unsigned* __restrict__ ctr)
{
    const int bx = blockIdx.x;
    const int grp = (bx & 7) | ((bx >> 7) << 3);   // batch group: 64 rows
    const int member = (bx >> 3) & 15;             // j-block within group
    const int b0 = grp * 64;
    const int j0 = member * 32;
    const int tid = threadIdx.x;
    const int lane = tid & 63;
    const int w = tid >> 6;
    const int wm = w & 1, wn = w >> 1;
    const int col = lane & 15, quad = lane >> 4;
    const int jj = j0 + wn * 16 + col;

    // [buf][row][k]; row stride 72 halves: frag b128 reads conflict-free.
    __shared__ _Float16 Abuf[2][64][72];

    // ---- loop-invariant state ----
    float bias[4];
    #pragma unroll
    for (int g = 0; g < 4; ++g) bias[g] = b_ih[g * HH + jj] + b_hh[g * HH + jj];

    const int arow = tid >> 2, aseg = (tid & 3) << 4;
    const size_t aoff = (size_t)(b0 + arow) * HH + aseg;
    const _Float16* a0 = h0g + aoff;    // A staging base per h-plane
    const _Float16* a1 = h1g + aoff;

    const half8* WT8 = (const half8*)WT;
    int bidx[4];
    #pragma unroll
    for (int g = 0; g < 4; ++g) bidx[g] = quad * 2048 + g * HH + jj;

    // h store base: rows b0+wm*32+quad*4 (+ tm*16 + reg)
    const size_t soff = (size_t)(b0 + wm * 32 + quad * 4) * HH + jj;
    _Float16* s0 = h0g + soff;
    _Float16* s1 = h1g + soff;

    unsigned* cnt = ctr + grp * 16;     // 64B-padded counter per group

    float cv[2][4] = {{0.f,0.f,0.f,0.f},{0.f,0.f,0.f,0.f}};  // c in registers

    const float* mp[2];
    #pragma unroll
    for (int tm = 0; tm < 2; ++tm)
        mp[tm] = msg + (size_t)(b0 + wm * 32 + tm * 16 + col) * TT * VV;

    // x-values for t=0 (direct A-fragment layout: row=...+col, k=quad*8+j)
    float xv[2][8];
    #pragma unroll
    for (int tm = 0; tm < 2; ++tm)
        #pragma unroll
        for (int j = 0; j < 8; ++j) {
            int k = quad * 8 + j;
            xv[tm][j] = (k < VV) ? mp[tm][k] : 0.0f;
        }

    half8 Bs[2][4];
    #pragma unroll
    for (int g = 0; g < 4; ++g) Bs[0][g] = WT8[16 * 8192 + bidx[g]];  // x-tail B (t=0)

    for (int t = 0; t < TT; ++t) {
        f32x4 acc[2][4];
        #pragma unroll
        for (int g = 0; g < 4; ++g) {
            f32x4 bv = {bias[g], bias[g], bias[g], bias[g]};
            acc[0][g] = bv;
            acc[1][g] = bv;
        }

        if (t > 0) {   // h-projection (t=0: h==0, skip; cv==0 handles c)
            const _Float16* aph = (t & 1) ? a1 : a0;   // hin = hb[t&1]

            // prologue: A chunk0 -> LDS buf0; chunk1 -> ra. (Bs[0]=c0,
            // Bs[1]=c1 were prefetched before the previous barrier.)
            half8 ra0 = gload_l2(aph);
            half8 ra1 = gload_l2(aph + 8);
            wait_vm0();
            *(half8*)&Abuf[0][arow][aseg]     = ra0;
            *(half8*)&Abuf[0][arow][aseg + 8] = ra1;
            ra0 = gload_l2(aph + 64);
            ra1 = gload_l2(aph + 72);
            bar_lgkm();

            #pragma unroll
            for (int it = 0; it < 8; ++it) {
                const int buf = it & 1;
                #pragma unroll
                for (int kk = 0; kk < 2; ++kk) {
                    const int cc = it * 2 + kk;   // K32 chunk 0..15
                    const int sl = cc & 1;
                    half8 ahf[2];
                    #pragma unroll
                    for (int tm = 0; tm < 2; ++tm)
                        ahf[tm] = *(const half8*)&Abuf[buf][wm * 32 + tm * 16 + col][kk * 32 + quad * 8];
                    #pragma unroll
                    for (int tm = 0; tm < 2; ++tm)
                        #pragma unroll
                        for (int g = 0; g < 4; ++g)
                            acc[tm][g] = __builtin_amdgcn_mfma_f32_16x16x32_f16(ahf[tm], Bs[sl][g], acc[tm][g], 0, 0, 0);
                    const int pf = cc + 2;        // chunk 16 = Wih tail
                    if (pf <= 16) {
                        #pragma unroll
                        for (int g = 0; g < 4; ++g) Bs[sl][g] = WT8[pf * 8192 + bidx[g]];
                    }
                }
                if (it < 7) {
                    wait_vm8();   // ra retired; 8 B loads stay in flight
                    *(half8*)&Abuf[buf ^ 1][arow][aseg]     = ra0;
                    *(half8*)&Abuf[buf ^ 1][arow][aseg + 8] = ra1;
                    if (it < 6) {
                        ra0 = gload_l2(aph + (it + 2) * 64);
                        ra1 = gload_l2(aph + (it + 2) * 64 + 8);
                    }
                    bar_lgkm();
                }
            }
        }

        // ---- x-projection tail: chunk 16 in Bs[0] ----
        {
            half8 ahf[2];
            #pragma unroll
            for (int tm = 0; tm < 2; ++tm) {
                half8 xh;
                #pragma unroll
                for (int j = 0; j < 8; ++j) xh[j] = (_Float16)xv[tm][j];
                ahf[tm] = xh;
            }
            #pragma unroll
            for (int tm = 0; tm < 2; ++tm)
                #pragma unroll
                for (int g = 0; g < 4; ++g)
                    acc[tm][g] = __builtin_amdgcn_mfma_f32_16x16x32_f16(ahf[tm], Bs[0][g], acc[tm][g], 0, 0, 0);
        }

        // ---- cell update: c in registers; plain h stores (write-through
        // L1 -> XCD L2, the coherence point for this group) ----
        // C/D layout: col=lane&15 (=n), row=quad*4+reg  [m89]
        _Float16* hop = (t & 1) ? s0 : s1;      // hout = hb[(t&1)^1]
        #pragma unroll
        for (int tm = 0; tm < 2; ++tm)
            #pragma unroll
            for (int reg = 0; reg < 4; ++reg) {
                float i_ = fsigmoid(acc[tm][0][reg]);
                float f_ = fsigmoid(acc[tm][1][reg]);
                float g_ = ftanh(acc[tm][2][reg]);
                float o_ = fsigmoid(acc[tm][3][reg]);
                float cn = __builtin_fmaf(f_, cv[tm][reg], i_ * g_);
                cv[tm][reg] = cn;
                hop[(size_t)(tm * 16 + reg) * HH] = (_Float16)(o_ * ftanh(cn));
            }

        if (t + 1 < TT) {
            // ---- t+1 prefetch (h-independent; lands during the spin) ----
            #pragma unroll
            for (int tm = 0; tm < 2; ++tm) mp[tm] += VV;
            #pragma unroll
            for (int tm = 0; tm < 2; ++tm)
                #pragma unroll
                for (int j = 0; j < 8; ++j) {
                    int k = quad * 8 + j;
                    xv[tm][j] = (k < VV) ? mp[tm][k] : 0.0f;
                }
            #pragma unroll
            for (int g = 0; g < 4; ++g) {
                Bs[0][g] = WT8[bidx[g]];
                Bs[1][g] = WT8[8192 + bidx[g]];
            }

            // ---- group barrier (all members same XCD -> L2-coherent) ----
            __syncthreads();   // vmcnt(0): h stores retired into XCD L2
            if (tid == 0) {
                __hip_atomic_fetch_add(cnt, 1u, __ATOMIC_RELAXED, __HIP_MEMORY_SCOPE_AGENT);
                const unsigned tgt = 16u * (unsigned)(t + 1);
                while (__hip_atomic_load(cnt, __ATOMIC_RELAXED, __HIP_MEMORY_SCOPE_AGENT) < tgt)
                    __builtin_amdgcn_s_sleep(2);
            }
            __syncthreads();
        }
    }
}

// out[b, cls] = dot(h, W_fc[cls]) + b_fc[cls]. 4 rows/block.
__global__ __launch_bounds__(256) void fc_kernel(
    const _Float16* __restrict__ h, const float* __restrict__ W_fc,
    const float* __restrict__ b_fc, float* __restrict__ out)
{
    __shared__ float hs[4][HH];
    const int b0 = blockIdx.x * 4;
    for (int i = threadIdx.x; i < 4 * HH; i += 256) {
        int r = i >> 9, k = i & 511;
        hs[r][k] = (float)h[(size_t)(b0 + r) * HH + k];
    }
    __syncthreads();
    const int tid = threadIdx.x;
    if (tid < 2 * NC) {
        int r = tid / NC, cls = tid % NC;
        const float4* wv = (const float4*)(W_fc + (size_t)cls * HH);
        const float4* h0 = (const float4*)hs[r];
        const float4* h1 = (const float4*)hs[r + 2];
        float s0 = 0.0f, s1 = 0.0f;
        #pragma unroll 4
        for (int k = 0; k < HH / 4; ++k) {
            float4 ww = wv[k];
            float4 a0 = h0[k], a1 = h1[k];
            s0 += a0.x * ww.x + a0.y * ww.y + a0.z * ww.z + a0.w * ww.w;
            s1 += a1.x * ww.x + a1.y * ww.y + a1.z * ww.z + a1.w * ww.w;
        }
        out[(size_t)(b0 + r) * NC + cls] = s0 + b_fc[cls];
        out[(size_t)(b0 + r + 2) * NC + cls] = s1 + b_fc[cls];
    }
}

extern "C" void kernel_launch(void* const* d_in, const int* in_sizes, int n_in,
                              void* d_out, int out_size, void* d_ws, size_t ws_size,
                              hipStream_t stream) {
    const float* msg  = (const float*)d_in[0];
    const float* W_ih = (const float*)d_in[1];
    const float* W_hh = (const float*)d_in[2];
    const float* b_ih = (const float*)d_in[3];
    const float* b_hh = (const float*)d_in[4];
    const float* W_fc = (const float*)d_in[5];
    const float* b_fc = (const float*)d_in[6];
    float* out = (float*)d_out;

    // ws: h0 h1 (fp16, 2MB ea) | WT (fp16, 2.23MB) | ctr (2KB). c is in
    // registers; t==0 reads neither h nor c, so no big memset.
    _Float16* h0 = (_Float16*)d_ws;
    _Float16* h1 = h0 + (size_t)BB * HH;
    _Float16* WT = h1 + (size_t)BB * HH;
    unsigned* ctr = (unsigned*)(WT + (size_t)68 * 2048 * 8);

    hipMemsetAsync(ctr, 0, 32 * 16 * sizeof(unsigned), stream);

    prep_whh_t<<<512, 256, 0, stream>>>(W_hh, WT);
    prep_wih_t<<<32, 256, 0, stream>>>(W_ih, WT);

    lstm_persist<<<512, 256, 0, stream>>>(msg, WT, b_ih, b_hh, h0, h1, ctr);

    // t=127 (odd) writes h0
    fc_kernel<<<BB / 4, 256, 0, stream>>>(h0, W_fc, b_fc, out);
}

// Round 6
// 1382.510 us; speedup vs baseline: 2.3448x; 1.3988x over previous
//
#include <hip/hip_runtime.h>

// Problem constants
#define BB 2048   // batch
#define TT 128    // timesteps
#define VV 25     // input features
#define HH 512    // hidden
#define NC 100    // classes

typedef __attribute__((ext_vector_type(8))) _Float16 half8;
typedef __attribute__((ext_vector_type(4))) float f32x4;

__device__ __forceinline__ float fsigmoid(float x) { return 1.0f / (1.0f + __expf(-x)); }
__device__ __forceinline__ float ftanh(float x) {
    float e = __expf(2.0f * x);
    return 1.0f - 2.0f / (e + 1.0f);
}

// ---- XCD-L2-coherent h exchange (round-5-proven) ----
// Group blocks share one XCD (bx%8 round-robin remap); h stores are plain
// (write-through L1 -> XCD L2), h loads sc0 (bypass stale per-CU L1, hit
// XCD L2). Validated: round 5 passed with absmax identical to the
// launch-per-step scheme.
__device__ __forceinline__ half8 gload_l2(const _Float16* p) {
    half8 r;
    asm volatile("global_load_dwordx4 %0, %1, off sc0" : "=v"(r) : "v"(p) : "memory");
    return r;
}
__device__ __forceinline__ void wait_vm0() {
    asm volatile("s_waitcnt vmcnt(0)" ::: "memory");
    __builtin_amdgcn_sched_barrier(0);
}
// counted wait: ra (2 asm loads) retired; this-iteration's 8 B-weight loads
// stay in flight (the only vm ops issued after ra).
__device__ __forceinline__ void wait_vm8() {
    asm volatile("s_waitcnt vmcnt(8)" ::: "memory");
    __builtin_amdgcn_sched_barrier(0);
}
// LDS-only barrier (global prefetches stay in flight across it).
__device__ __forceinline__ void bar_lgkm() {
    asm volatile("s_waitcnt lgkmcnt(0)" ::: "memory");
    __builtin_amdgcn_sched_barrier(0);
    __builtin_amdgcn_s_barrier();
    asm volatile("" ::: "memory");
}

// ---- prep: weights -> MFMA-fragment-native fp16 layout ----
__global__ __launch_bounds__(256) void prep_whh_t(const float* __restrict__ W,
                                                  _Float16* __restrict__ WT) {
    int i = blockIdx.x * 256 + threadIdx.x;   // 2048 n x 64 kq, grid 512
    int n = i & 2047, kq = i >> 11;
    half8 h8;
    #pragma unroll
    for (int j = 0; j < 8; ++j) h8[j] = (_Float16)W[(size_t)n * HH + kq * 8 + j];  // RNE cvt
    ((half8*)WT)[(size_t)kq * 2048 + n] = h8;
}

__global__ __launch_bounds__(256) void prep_wih_t(const float* __restrict__ W,
                                                  _Float16* __restrict__ WT) {
    int i = blockIdx.x * 256 + threadIdx.x;   // 2048 n x 4 kq, grid 32
    int n = i & 2047, kq4 = i >> 11;
    half8 h8;
    #pragma unroll
    for (int j = 0; j < 8; ++j) {
        int k = kq4 * 8 + j;
        h8[j] = (k < VV) ? (_Float16)W[(size_t)n * VV + k] : (_Float16)0.0f;
    }
    ((half8*)WT)[(size_t)(64 + kq4) * 2048 + n] = h8;
}

// Persistent LSTM, round 6: round 5's proven dataflow with the barrier
// rebuilt RMW-free and the wait overlapped with useful work.
//
// Barrier (per group of 16 blocks, per step):
//   arrival:  __syncthreads() [drains vmcnt -> h stores in L2], then
//             tid0 stores flag[grp][member] = t+1 (plain store, sc0sc1 —
//             fabric-coherent, 16 INDEPENDENT lines, no RMW, no
//             serialization; round 5's 16 same-address fabric atomic adds
//             serialized ~0.5us each = the 13us/step overhead).
//   overlap:  x-values(t+1) load, acc = bias + x@Wih MFMA (chunk-16 B
//             frags permanent in Bx regs), B chunk-0/1 prefetch — all
//             h-independent, hides flag propagation.
//   depart:   wave0 lanes0-15 poll all 16 flags with ONE vector
//             global_load_dword per iteration + __all ballot; then
//             __syncthreads().
// Safety: skew within a group is provably <= 1 step (flag t+2 requires all
// members through step t+1), so the 2-plane h double-buffer suffices —
// same argument as the counter barrier, unchanged.
__global__ __launch_bounds__(256, 2) void lstm_persist(
    const float* __restrict__ msg,
    const _Float16* __restrict__ WT,
    const float* __restrict__ b_ih, const float* __restrict__ b_hh,
    _Float16* __restrict__ h0g, _Float16* __restrict__ h1g,
    unsigned* __restrict__ ctr)
{
    const int bx = blockIdx.x;
    const int grp = (bx & 7) | ((bx >> 7) << 3);   // batch group: 64 rows
    const int member = (bx >> 3) & 15;             // j-block within group
    const int b0 = grp * 64;
    const int j0 = member * 32;
    const int tid = threadIdx.x;
    const int lane = tid & 63;
    const int w = tid >> 6;
    const int wm = w & 1, wn = w >> 1;
    const int col = lane & 15, quad = lane >> 4;
    const int jj = j0 + wn * 16 + col;

    // [buf][row][k]; row stride 72 halves: frag b128 reads conflict-free.
    __shared__ _Float16 Abuf[2][64][72];

    // ---- loop-invariant state ----
    float bias[4];
    #pragma unroll
    for (int g = 0; g < 4; ++g) bias[g] = b_ih[g * HH + jj] + b_hh[g * HH + jj];

    const int arow = tid >> 2, aseg = (tid & 3) << 4;
    const size_t aoff = (size_t)(b0 + arow) * HH + aseg;
    const _Float16* a0 = h0g + aoff;    // A staging base per h-plane
    const _Float16* a1 = h1g + aoff;

    const half8* WT8 = (const half8*)WT;
    int bidx[4];
    #pragma unroll
    for (int g = 0; g < 4; ++g) bidx[g] = quad * 2048 + g * HH + jj;

    // h store base: rows b0+wm*32+quad*4 (+ tm*16 + reg)
    const size_t soff = (size_t)(b0 + wm * 32 + quad * 4) * HH + jj;
    _Float16* s0 = h0g + soff;
    _Float16* s1 = h1g + soff;

    // per-member flag words, 64B apart
    unsigned* myflag = ctr + (grp * 16 + member) * 16;
    unsigned* pollflag = ctr + (grp * 16 + (lane & 15)) * 16;

    float cv[2][4] = {{0.f,0.f,0.f,0.f},{0.f,0.f,0.f,0.f}};  // c in registers

    const float* mp[2];
    #pragma unroll
    for (int tm = 0; tm < 2; ++tm)
        mp[tm] = msg + (size_t)(b0 + wm * 32 + tm * 16 + col) * TT * VV;

    // chunk-16 (x-projection) B frags: constant across steps, keep in regs
    half8 Bx[4];
    #pragma unroll
    for (int g = 0; g < 4; ++g) Bx[g] = WT8[16 * 8192 + bidx[g]];

    half8 Bs[2][4];
    f32x4 acc[2][4];   // [tm][gate]; at loop entry for step t: bias + x_t@Wih

    // ---- pre-loop: acc for t=0 ----
    {
        float xv[2][8];
        #pragma unroll
        for (int tm = 0; tm < 2; ++tm)
            #pragma unroll
            for (int j = 0; j < 8; ++j) {
                int k = quad * 8 + j;
                xv[tm][j] = (k < VV) ? mp[tm][k] : 0.0f;
            }
        #pragma unroll
        for (int g = 0; g < 4; ++g) {
            f32x4 bv = {bias[g], bias[g], bias[g], bias[g]};
            acc[0][g] = bv;
            acc[1][g] = bv;
        }
        #pragma unroll
        for (int tm = 0; tm < 2; ++tm) {
            half8 xh;
            #pragma unroll
            for (int j = 0; j < 8; ++j) xh[j] = (_Float16)xv[tm][j];
            #pragma unroll
            for (int g = 0; g < 4; ++g)
                acc[tm][g] = __builtin_amdgcn_mfma_f32_16x16x32_f16(xh, Bx[g], acc[tm][g], 0, 0, 0);
        }
    }

    for (int t = 0; t < TT; ++t) {
        if (t > 0) {   // h-projection: 16 K32 chunks over h_{t-1}
            const _Float16* aph = (t & 1) ? a1 : a0;   // hin plane

            // prologue: A chunk0 -> LDS buf0; chunk1 -> ra. (Bs[0]=c0,
            // Bs[1]=c1 were prefetched in the previous barrier window.)
            half8 ra0 = gload_l2(aph);
            half8 ra1 = gload_l2(aph + 8);
            wait_vm0();
            *(half8*)&Abuf[0][arow][aseg]     = ra0;
            *(half8*)&Abuf[0][arow][aseg + 8] = ra1;
            ra0 = gload_l2(aph + 64);
            ra1 = gload_l2(aph + 72);
            bar_lgkm();

            #pragma unroll
            for (int it = 0; it < 8; ++it) {
                const int buf = it & 1;
                #pragma unroll
                for (int kk = 0; kk < 2; ++kk) {
                    const int cc = it * 2 + kk;   // K32 chunk 0..15
                    const int sl = cc & 1;
                    half8 ahf[2];
                    #pragma unroll
                    for (int tm = 0; tm < 2; ++tm)
                        ahf[tm] = *(const half8*)&Abuf[buf][wm * 32 + tm * 16 + col][kk * 32 + quad * 8];
                    #pragma unroll
                    for (int tm = 0; tm < 2; ++tm)
                        #pragma unroll
                        for (int g = 0; g < 4; ++g)
                            acc[tm][g] = __builtin_amdgcn_mfma_f32_16x16x32_f16(ahf[tm], Bs[sl][g], acc[tm][g], 0, 0, 0);
                    const int pf = cc + 2;        // chunks 2..15 in-loop
                    if (pf <= 15) {
                        #pragma unroll
                        for (int g = 0; g < 4; ++g) Bs[sl][g] = WT8[pf * 8192 + bidx[g]];
                    }
                }
                if (it < 7) {
                    wait_vm8();   // ra retired; 8 B loads stay in flight
                    *(half8*)&Abuf[buf ^ 1][arow][aseg]     = ra0;
                    *(half8*)&Abuf[buf ^ 1][arow][aseg + 8] = ra1;
                    if (it < 6) {
                        ra0 = gload_l2(aph + (it + 2) * 64);
                        ra1 = gload_l2(aph + (it + 2) * 64 + 8);
                    }
                    bar_lgkm();
                }
            }
        }

        // ---- cell update: c in registers; plain h stores -> XCD L2 ----
        // C/D layout: col=lane&15 (=n), row=quad*4+reg  [m89]
        _Float16* hop = (t & 1) ? s0 : s1;      // h_t plane
        #pragma unroll
        for (int tm = 0; tm < 2; ++tm)
            #pragma unroll
            for (int reg = 0; reg < 4; ++reg) {
                float i_ = fsigmoid(acc[tm][0][reg]);
                float f_ = fsigmoid(acc[tm][1][reg]);
                float g_ = ftanh(acc[tm][2][reg]);
                float o_ = fsigmoid(acc[tm][3][reg]);
                float cn = __builtin_fmaf(f_, cv[tm][reg], i_ * g_);
                cv[tm][reg] = cn;
                hop[(size_t)(tm * 16 + reg) * HH] = (_Float16)(o_ * ftanh(cn));
            }

        if (t + 1 < TT) {
            // ---- arrival: drain h stores, then one flag store (no RMW) ----
            __syncthreads();   // vmcnt(0): h_t retired into XCD L2
            if (tid == 0) {
                unsigned v = (unsigned)(t + 1);
                asm volatile("global_store_dword %0, %1, off sc0 sc1"
                             :: "v"(myflag), "v"(v) : "memory");
            }

            // ---- overlap window: all h-independent t+1 work ----
            #pragma unroll
            for (int tm = 0; tm < 2; ++tm) mp[tm] += VV;
            float xv[2][8];
            #pragma unroll
            for (int tm = 0; tm < 2; ++tm)
                #pragma unroll
                for (int j = 0; j < 8; ++j) {
                    int k = quad * 8 + j;
                    xv[tm][j] = (k < VV) ? mp[tm][k] : 0.0f;
                }
            #pragma unroll
            for (int g = 0; g < 4; ++g) {
                f32x4 bv = {bias[g], bias[g], bias[g], bias[g]};
                acc[0][g] = bv;
                acc[1][g] = bv;
            }
            #pragma unroll
            for (int tm = 0; tm < 2; ++tm) {
                half8 xh;
                #pragma unroll
                for (int j = 0; j < 8; ++j) xh[j] = (_Float16)xv[tm][j];
                #pragma unroll
                for (int g = 0; g < 4; ++g)
                    acc[tm][g] = __builtin_amdgcn_mfma_f32_16x16x32_f16(xh, Bx[g], acc[tm][g], 0, 0, 0);
            }
            #pragma unroll
            for (int g = 0; g < 4; ++g) {
                Bs[0][g] = WT8[bidx[g]];
                Bs[1][g] = WT8[8192 + bidx[g]];
            }

            // ---- departure: wave0 polls all 16 flags in one load/iter ----
            if (w == 0) {
                const unsigned tgt = (unsigned)(t + 1);
                for (;;) {
                    unsigned f;
                    asm volatile("global_load_dword %0, %1, off sc0 sc1\n\t"
                                 "s_waitcnt vmcnt(0)"
                                 : "=v"(f) : "v"(pollflag) : "memory");
                    if (__all((int)(f >= tgt))) break;
                    __builtin_amdgcn_s_sleep(1);
                }
                __builtin_amdgcn_sched_barrier(0);
            }
            __syncthreads();
        }
    }
}

// out[b, cls] = dot(h, W_fc[cls]) + b_fc[cls]. 4 rows/block.
__global__ __launch_bounds__(256) void fc_kernel(
    const _Float16* __restrict__ h, const float* __restrict__ W_fc,
    const float* __restrict__ b_fc, float* __restrict__ out)
{
    __shared__ float hs[4][HH];
    const int b0 = blockIdx.x * 4;
    for (int i = threadIdx.x; i < 4 * HH; i += 256) {
        int r = i >> 9, k = i & 511;
        hs[r][k] = (float)h[(size_t)(b0 + r) * HH + k];
    }
    __syncthreads();
    const int tid = threadIdx.x;
    if (tid < 2 * NC) {
        int r = tid / NC, cls = tid % NC;
        const float4* wv = (const float4*)(W_fc + (size_t)cls * HH);
        const float4* h0 = (const float4*)hs[r];
        const float4* h1 = (const float4*)hs[r + 2];
        float s0 = 0.0f, s1 = 0.0f;
        #pragma unroll 4
        for (int k = 0; k < HH / 4; ++k) {
            float4 ww = wv[k];
            float4 a0 = h0[k], a1 = h1[k];
            s0 += a0.x * ww.x + a0.y * ww.y + a0.z * ww.z + a0.w * ww.w;
            s1 += a1.x * ww.x + a1.y * ww.y + a1.z * ww.z + a1.w * ww.w;
        }
        out[(size_t)(b0 + r) * NC + cls] = s0 + b_fc[cls];
        out[(size_t)(b0 + r + 2) * NC + cls] = s1 + b_fc[cls];
    }
}

extern "C" void kernel_launch(void* const* d_in, const int* in_sizes, int n_in,
                              void* d_out, int out_size, void* d_ws, size_t ws_size,
                              hipStream_t stream) {
    const float* msg  = (const float*)d_in[0];
    const float* W_ih = (const float*)d_in[1];
    const float* W_hh = (const float*)d_in[2];
    const float* b_ih = (const float*)d_in[3];
    const float* b_hh = (const float*)d_in[4];
    const float* W_fc = (const float*)d_in[5];
    const float* b_fc = (const float*)d_in[6];
    float* out = (float*)d_out;

    // ws: h0 h1 (fp16, 2MB ea) | WT (fp16, 2.23MB) | flags (32KB)
    _Float16* h0 = (_Float16*)d_ws;
    _Float16* h1 = h0 + (size_t)BB * HH;
    _Float16* WT = h1 + (size_t)BB * HH;
    unsigned* ctr = (unsigned*)(WT + (size_t)68 * 2048 * 8);

    hipMemsetAsync(ctr, 0, 32 * 16 * 16 * sizeof(unsigned), stream);

    prep_whh_t<<<512, 256, 0, stream>>>(W_hh, WT);
    prep_wih_t<<<32, 256, 0, stream>>>(W_ih, WT);

    lstm_persist<<<512, 256, 0, stream>>>(msg, WT, b_ih, b_hh, h0, h1, ctr);

    // t=127 (odd) writes h0
    fc_kernel<<<BB / 4, 256, 0, stream>>>(h0, W_fc, b_fc, out);
}